// Round 16
// baseline (5967.376 us; speedup 1.0000x reference)
//
#include <hip/hip_runtime.h>
#include <hip/hip_bf16.h>
#include <math.h>

// DiffusionFlow: fused 10-step flow + log-det on MI355X.
// Round 16 = r15 (zero-spill, 32 samples/WG, 1024 thr / 16 waves, 32x32x16
// intrinsic MFMA, acc in AGPR, minimal-live K-loop) + CONFLICT-FREE LDS:
// the b128 B-read at row-stride 1024 was a pigeonhole 4-way bank conflict
// (32 rows -> 8 quads; 6.13e8 conflict cycles, ~1ms). New layout:
//   byte(row, kb) = row*1024 + (kb ^ ((row&15)<<3)),  8B granularity
// accessed as 2x ds_read_b64 -> 32 rows over 16 bank-pairs = 2-way = free.
// Same function at ALL sites (L0 write, K read, epi write, L3 read);
// rows +32/+64 share the swizzle since (row+32)&15 == row&15.

typedef float  f32x4  __attribute__((ext_vector_type(4)));
typedef float  f32x16 __attribute__((ext_vector_type(16)));
typedef __bf16 bf16x8 __attribute__((ext_vector_type(8)));

static __device__ __forceinline__ unsigned pkbf2(float a, float b) {
    unsigned short lo = __builtin_bit_cast(unsigned short, __float2bfloat16(a));
    unsigned short hi = __builtin_bit_cast(unsigned short, __float2bfloat16(b));
    return (unsigned)lo | ((unsigned)hi << 16);
}

// ---- pack W (512x512 row-major fp32) -> bf16 A-frag order for 32x32x16 ----
// out[(((c*16+nb)*64)+l)*8+j] = W[nb*32+(l&31)][c*16+(l>>5)*8+j]  (verified r5-r15)
__global__ void pack_w_kernel(const float* __restrict__ W,
                              __hip_bfloat16* __restrict__ out) {
    int i  = blockIdx.x * 512 + threadIdx.x;
    int c  = i >> 13;
    int nb = (i >> 9) & 15;
    int l  = (i >> 3) & 63;
    int j  = i & 7;
    int n  = nb * 32 + (l & 31);
    int k  = c * 16 + ((l >> 5) << 3) + j;
    out[i] = __float2bfloat16(W[n * 512 + k]);
}

// ---- pack W0 cols 0,1 -> contiguous [512][2] fp32 ----
__global__ void pack_w0_kernel(const float* __restrict__ W0,
                               float* __restrict__ w01) {
    int o = threadIdx.x;
    w01[o * 2 + 0] = W0[o * 34 + 0];
    w01[o * 2 + 1] = W0[o * 34 + 1];
}

// ---- c_step[k][o] = b0[o] + W0[o,2:34] . temb(t_k) ----
__global__ void cstep_kernel(const float* __restrict__ W0,
                             const float* __restrict__ b0,
                             float* __restrict__ cst) {
    int k = blockIdx.x;
    int o = threadIdx.x;
    float t = (float)k * 0.1f;
    float acc = b0[o];
    #pragma unroll
    for (int j = 0; j < 16; ++j) {
        float f   = expf(-9.210340371976184f * (float)j / 16.0f);
        float arg = t * f;
        acc += W0[o * 34 + 2 + j]  * sinf(arg);
        acc += W0[o * 34 + 18 + j] * cosf(arg);
    }
    cst[k * 512 + o] = acc;
}

__global__ __launch_bounds__(1024)
void flow_kernel(const float* __restrict__ x,
                 const float* __restrict__ w01,
                 const float* __restrict__ cst,
                 const __hip_bfloat16* __restrict__ Wpk1,
                 const __hip_bfloat16* __restrict__ Wpk2,
                 const float* __restrict__ b1,
                 const float* __restrict__ b2,
                 const float* __restrict__ W3,
                 const float* __restrict__ b3v,
                 float* __restrict__ out)
{
    __shared__ __align__(16) __hip_bfloat16 Xbuf[96 * 512];  // 96 KB
    __shared__ float zbuf[32][2];
    __shared__ float ldbuf[32];

    const int tid  = threadIdx.x;
    const int lane = tid & 63;
    const int wid  = tid >> 6;        // 0..15 -> cols [wid*32, wid*32+32)
    const int l31  = lane & 31;
    const int hi   = lane >> 5;       // 0/1
    const int n0w  = wid << 5;
    const int wgs  = blockIdx.x << 5; // 32 samples per WG

    if (tid < 32) {
        zbuf[tid][0] = x[(wgs + tid) * 2 + 0];
        zbuf[tid][1] = x[(wgs + tid) * 2 + 1];
        ldbuf[tid]   = 0.0f;
    }

    // layout: byte(row, kb) = row*1024 + (kb ^ ((row&15)<<3)), 8B granules.
    const int swzR = (l31 & 15) << 3;       // K-read / epi-write rows (l31 family)
    const int s3   = swzR & 8;
    const int sHi  = swzR & 0x70;
    const int b0a  = (l31 << 10) + s3;          // row l31, half0
    const int b0b  = (l31 << 10) + (8 ^ s3);    // row l31, half1
    const int b1a  = ((32 + l31) << 10) + s3;
    const int b1b  = ((32 + l31) << 10) + (8 ^ s3);
    const int b2a  = ((64 + l31) << 10) + s3;
    const int b2b  = ((64 + l31) << 10) + (8 ^ s3);
    const int hi16 = hi << 4;
    // A-frag: uint4 index = c*1024 + abase  (wave wid owns n-block wid)
    const int abase = (wid << 6) + lane;
    const uint4* Wp1 = (const uint4*)Wpk1;
    const uint4* Wp2 = (const uint4*)Wpk2;

    // L0/L3 split: s0 = sample (tid>>5, 0..31), t32 = 32-way column split
    const int s0   = tid >> 5;
    const int t32  = tid & 31;
    const int swz0 = (s0 & 15) << 3;

    const char* xb = (const char*)Xbuf;

    __syncthreads();

    #pragma unroll 1
    for (int step = 0; step < 10; ++step) {
        // ---------- layer 0: rank-2 + step-constant, 16 outs/thread ----------
        {
            const float z0 = zbuf[s0][0];
            const float z1 = zbuf[s0][1];
            const float* cs = cst + (step << 9);
            char* base0 = (char*)Xbuf + (s0 << 10);
            #pragma unroll 1
            for (int m = 0; m < 2; ++m) {
                int ob = (t32 << 4) + (m << 3);    // element base, 8 outs
                const float4* wv4 = (const float4*)(w01 + (ob << 1));
                const float4* cv4 = (const float4*)(cs + ob);
                unsigned ph[4], p0[4], p1[4];
                #pragma unroll
                for (int jj = 0; jj < 4; ++jj) {
                    float4 wv = wv4[jj];                    // pairs (x,y),(z,w)
                    float4 cv = cv4[jj >> 1];
                    float c0 = (jj & 1) ? cv.z : cv.x;
                    float c1 = (jj & 1) ? cv.w : cv.y;
                    float a0  = fmaf(z0, wv.x, fmaf(z1, wv.y, c0));
                    float sg0 = 1.0f / (1.0f + __expf(-a0));
                    float h0  = a0 * sg0;
                    float sp0 = fmaf(h0, 1.0f - sg0, sg0);  // silu'(a0)
                    float a1  = fmaf(z0, wv.z, fmaf(z1, wv.w, c1));
                    float sg1 = 1.0f / (1.0f + __expf(-a1));
                    float h1  = a1 * sg1;
                    float sp1 = fmaf(h1, 1.0f - sg1, sg1);
                    ph[jj] = pkbf2(h0, h1);
                    p0[jj] = pkbf2(sp0 * wv.x, sp1 * wv.z);
                    p1[jj] = pkbf2(sp0 * wv.y, sp1 * wv.w);
                }
                int kb   = ob << 1;                 // 16B-aligned (bit3 = 0)
                int offA = kb ^ swz0;
                int offB = (kb + 8) ^ swz0;
                uint2 vhA = {ph[0], ph[1]}, vhB = {ph[2], ph[3]};
                uint2 v0A = {p0[0], p0[1]}, v0B = {p0[2], p0[3]};
                uint2 v1A = {p1[0], p1[1]}, v1B = {p1[2], p1[3]};
                *(uint2*)(base0 + offA)              = vhA;
                *(uint2*)(base0 + offB)              = vhB;
                *(uint2*)(base0 + (32 << 10) + offA) = v0A;
                *(uint2*)(base0 + (32 << 10) + offB) = v0B;
                *(uint2*)(base0 + (64 << 10) + offA) = v1A;
                *(uint2*)(base0 + (64 << 10) + offB) = v1B;
            }
        }
        __syncthreads();

        // ---------- layers 1,2: D = W @ X^T via 32x32x16 MFMA (intrinsic) ----------
        #pragma unroll 1
        for (int layer = 0; layer < 2; ++layer) {
            const uint4* __restrict__ Wp   = layer ? Wp2 : Wp1;
            const float* __restrict__ bias = layer ? b2  : b1;

            f32x16 acc0 = (f32x16)(0.0f);   // h stream  (AGPR)
            f32x16 acc1 = (f32x16)(0.0f);   // u0
            f32x16 acc2 = (f32x16)(0.0f);   // u1

            // minimal-live K-loop: wrap-around depth-1 A prefetch, B just-in-time
            // as 6x ds_read_b64 (conflict-free: 16 bank-pair slots, 2-way).
            uint4 aCur = Wp[abase];
            #pragma unroll 2
            for (int c = 0; c < 32; ++c) {
                uint4 aNxt = Wp[abase + (((c + 1) & 31) << 10)];
                int kxs = ((c << 5) | hi16) ^ sHi;
                uint2 r0a = *(const uint2*)(xb + b0a + kxs);
                uint2 r0b = *(const uint2*)(xb + b0b + kxs);
                uint2 r1a = *(const uint2*)(xb + b1a + kxs);
                uint2 r1b = *(const uint2*)(xb + b1b + kxs);
                uint2 r2a = *(const uint2*)(xb + b2a + kxs);
                uint2 r2b = *(const uint2*)(xb + b2b + kxs);
                uint4 u0 = {r0a.x, r0a.y, r0b.x, r0b.y};
                uint4 u1 = {r1a.x, r1a.y, r1b.x, r1b.y};
                uint4 u2 = {r2a.x, r2a.y, r2b.x, r2b.y};
                bf16x8 bf0 = __builtin_bit_cast(bf16x8, u0);
                bf16x8 bf1 = __builtin_bit_cast(bf16x8, u1);
                bf16x8 bf2 = __builtin_bit_cast(bf16x8, u2);
                bf16x8 av  = __builtin_bit_cast(bf16x8, aCur);
                __builtin_amdgcn_s_setprio(1);
                acc0 = __builtin_amdgcn_mfma_f32_32x32x16_bf16(av, bf0, acc0, 0, 0, 0);
                acc1 = __builtin_amdgcn_mfma_f32_32x32x16_bf16(av, bf1, acc1, 0, 0, 0);
                acc2 = __builtin_amdgcn_mfma_f32_32x32x16_bf16(av, bf2, acc2, 0, 0, 0);
                __builtin_amdgcn_s_setprio(0);
                aCur = aNxt;
            }

            __syncthreads();   // all waves done reading Xbuf before overwrite

            // epilogue: silu + JVP coupling; D col = sample = l31,
            // D row n = n0w + (reg&3) + 8*(reg>>2) + 4*hi  (m74 layout, verified)
            {
                char* pb = (char*)Xbuf + (l31 << 10);
                #pragma unroll
                for (int q = 0; q < 4; ++q) {
                    int nq = n0w + 8 * q + 4 * hi;          // 4 consecutive n
                    f32x4 bq = *(const f32x4*)(bias + nq);
                    float hv[4], u0v[4], u1v[4];
                    #pragma unroll
                    for (int k = 0; k < 4; ++k) {
                        int reg = 4 * q + k;
                        float aa  = acc0[reg] + bq[k];
                        float sig = 1.0f / (1.0f + __expf(-aa));
                        float h   = aa * sig;
                        float sp  = fmaf(h, 1.0f - sig, sig);
                        hv[k]  = h;
                        u0v[k] = sp * acc1[reg];
                        u1v[k] = sp * acc2[reg];
                    }
                    int off = ((nq << 1) ^ swzR);           // 8B-aligned granule
                    uint2 vh = {pkbf2(hv[0],  hv[1]),  pkbf2(hv[2],  hv[3])};
                    uint2 v0 = {pkbf2(u0v[0], u0v[1]), pkbf2(u0v[2], u0v[3])};
                    uint2 v1 = {pkbf2(u1v[0], u1v[1]), pkbf2(u1v[2], u1v[3])};
                    *(uint2*)(pb + off)              = vh;
                    *(uint2*)(pb + (32 << 10) + off) = v0;
                    *(uint2*)(pb + (64 << 10) + off) = v1;
                }
            }
            __syncthreads();
        }

        // ---------- layer 3: six length-512 dots, two rolled 8-elem passes ----------
        {
            float d0 = 0.f, d1 = 0.f, d2 = 0.f, d3 = 0.f, d4 = 0.f, d5 = 0.f;
            #pragma unroll 1
            for (int p = 0; p < 2; ++p) {
                int eb = (t32 << 4) + (p << 3);    // element base, 8 elems
                const float4* wr0 = (const float4*)(W3 + eb);
                const float4* wr1 = (const float4*)(W3 + 512 + eb);
                float4 wa0 = wr0[0], wa1 = wr0[1];
                float4 wb0 = wr1[0], wb1 = wr1[1];
                int kb   = (t32 << 5) + (p << 4);  // 16B-aligned
                int offA = kb ^ swz0;
                int offB = (kb + 8) ^ swz0;
                #pragma unroll
                for (int st = 0; st < 3; ++st) {
                    const char* rb = xb + ((s0 + st * 32) << 10);
                    uint2 va = *(const uint2*)(rb + offA);
                    uint2 vb = *(const uint2*)(rb + offB);
                    float e0 = __uint_as_float(va.x << 16);
                    float e1 = __uint_as_float(va.x & 0xffff0000u);
                    float e2 = __uint_as_float(va.y << 16);
                    float e3 = __uint_as_float(va.y & 0xffff0000u);
                    float e4 = __uint_as_float(vb.x << 16);
                    float e5 = __uint_as_float(vb.x & 0xffff0000u);
                    float e6 = __uint_as_float(vb.y << 16);
                    float e7 = __uint_as_float(vb.y & 0xffff0000u);
                    float sa = wa0.x * e0;
                    sa = fmaf(wa0.y, e1, sa); sa = fmaf(wa0.z, e2, sa);
                    sa = fmaf(wa0.w, e3, sa); sa = fmaf(wa1.x, e4, sa);
                    sa = fmaf(wa1.y, e5, sa); sa = fmaf(wa1.z, e6, sa);
                    sa = fmaf(wa1.w, e7, sa);
                    float sb = wb0.x * e0;
                    sb = fmaf(wb0.y, e1, sb); sb = fmaf(wb0.z, e2, sb);
                    sb = fmaf(wb0.w, e3, sb); sb = fmaf(wb1.x, e4, sb);
                    sb = fmaf(wb1.y, e5, sb); sb = fmaf(wb1.z, e6, sb);
                    sb = fmaf(wb1.w, e7, sb);
                    if      (st == 0) { d0 += sa; d1 += sb; }
                    else if (st == 1) { d2 += sa; d3 += sb; }
                    else              { d4 += sa; d5 += sb; }
                }
            }
            #pragma unroll
            for (int m = 1; m < 32; m <<= 1) {
                d0 += __shfl_xor(d0, m);
                d1 += __shfl_xor(d1, m);
                d2 += __shfl_xor(d2, m);
                d3 += __shfl_xor(d3, m);
                d4 += __shfl_xor(d4, m);
                d5 += __shfl_xor(d5, m);
            }
            if (t32 == 0) {
                float v0 = d0 + b3v[0];
                float v1 = d1 + b3v[1];
                float det = (1.0f + 0.1f * d2) * (1.0f + 0.1f * d5)
                          - 0.01f * d4 * d3;
                ldbuf[s0] += logf(fmaxf(fabsf(det), 1e-8f));
                zbuf[s0][0] += 0.1f * v0;
                zbuf[s0][1] += 0.1f * v1;
            }
        }
        __syncthreads();
    }

    if (tid < 32) {
        float z0 = zbuf[tid][0], z1 = zbuf[tid][1];
        out[wgs + tid] = -0.5f * (z0 * z0 + z1 * z1) - 1.8378770664093453f + ldbuf[tid];
    }
}

extern "C" void kernel_launch(void* const* d_in, const int* in_sizes, int n_in,
                              void* d_out, int out_size, void* d_ws, size_t ws_size,
                              hipStream_t stream) {
    const float* x  = (const float*)d_in[0];
    const float* W0 = (const float*)d_in[1];   // (512, 34)
    const float* b0 = (const float*)d_in[2];
    const float* W1 = (const float*)d_in[3];   // (512, 512)
    const float* b1 = (const float*)d_in[4];
    const float* W2 = (const float*)d_in[5];
    const float* b2 = (const float*)d_in[6];
    const float* W3 = (const float*)d_in[7];   // (2, 512)
    const float* b3 = (const float*)d_in[8];
    float* out = (float*)d_out;

    char* ws = (char*)d_ws;
    __hip_bfloat16* wpk1 = (__hip_bfloat16*)ws;                  // 512 KB
    __hip_bfloat16* wpk2 = (__hip_bfloat16*)(ws + (512u << 10)); // 512 KB
    float*          cstp = (float*)(ws + (1024u << 10));         // 20 KB
    float*          w01p = (float*)(ws + (1044u << 10));         // 4 KB

    pack_w_kernel<<<512, 512, 0, stream>>>(W1, wpk1);
    pack_w_kernel<<<512, 512, 0, stream>>>(W2, wpk2);
    cstep_kernel<<<10, 512, 0, stream>>>(W0, b0, cstp);
    pack_w0_kernel<<<1, 512, 0, stream>>>(W0, w01p);
    flow_kernel<<<131072 / 32, 1024, 0, stream>>>(x, w01p, cstp, wpk1, wpk2,
                                                  b1, b2, W3, b3, out);
}

// Round 17
// 5324.086 us; speedup vs baseline: 1.1208x; 1.1208x over previous
//
#include <hip/hip_runtime.h>
#include <hip/hip_bf16.h>
#include <math.h>

// DiffusionFlow: fused 10-step flow + log-det on MI355X.
// Round 17 = r15 (best: 5.71ms, zero-spill, 32 samples/WG, 1024 thr/16 waves,
// 32x32x16 intrinsic MFMA acc-in-AGPR, minimal-live K-loop, b128 LDS reads)
// + FOLDED OUTPUT PROJECTION: layer-2 epilogue computes the six W3-dots
// register-locally from the accumulators (sample=l31, 16 cols/lane), merges
// hi-halves via shfl_xor(32), stores per-wave partials to part[16][32][8]
// (deterministic, no atomics); a 32-thread det phase sums the 16 waves.
// Eliminates: epi-2 LDS writes (96KB/step/CU), L3 LDS re-reads (96KB),
// L3 VALU + shuffles, and one barrier. r16's b64 split reverted (it cut
// conflicts 2x but added issue+pack overhead -> net regression).

typedef float  f32x4  __attribute__((ext_vector_type(4)));
typedef float  f32x16 __attribute__((ext_vector_type(16)));
typedef __bf16 bf16x8 __attribute__((ext_vector_type(8)));

static __device__ __forceinline__ unsigned pkbf2(float a, float b) {
    unsigned short lo = __builtin_bit_cast(unsigned short, __float2bfloat16(a));
    unsigned short hi = __builtin_bit_cast(unsigned short, __float2bfloat16(b));
    return (unsigned)lo | ((unsigned)hi << 16);
}

// ---- pack W (512x512 row-major fp32) -> bf16 A-frag order for 32x32x16 ----
// out[(((c*16+nb)*64)+l)*8+j] = W[nb*32+(l&31)][c*16+(l>>5)*8+j]  (verified r5-r16)
__global__ void pack_w_kernel(const float* __restrict__ W,
                              __hip_bfloat16* __restrict__ out) {
    int i  = blockIdx.x * 512 + threadIdx.x;
    int c  = i >> 13;
    int nb = (i >> 9) & 15;
    int l  = (i >> 3) & 63;
    int j  = i & 7;
    int n  = nb * 32 + (l & 31);
    int k  = c * 16 + ((l >> 5) << 3) + j;
    out[i] = __float2bfloat16(W[n * 512 + k]);
}

// ---- pack W0 cols 0,1 -> contiguous [512][2] fp32 ----
__global__ void pack_w0_kernel(const float* __restrict__ W0,
                               float* __restrict__ w01) {
    int o = threadIdx.x;
    w01[o * 2 + 0] = W0[o * 34 + 0];
    w01[o * 2 + 1] = W0[o * 34 + 1];
}

// ---- c_step[k][o] = b0[o] + W0[o,2:34] . temb(t_k) ----
__global__ void cstep_kernel(const float* __restrict__ W0,
                             const float* __restrict__ b0,
                             float* __restrict__ cst) {
    int k = blockIdx.x;
    int o = threadIdx.x;
    float t = (float)k * 0.1f;
    float acc = b0[o];
    #pragma unroll
    for (int j = 0; j < 16; ++j) {
        float f   = expf(-9.210340371976184f * (float)j / 16.0f);
        float arg = t * f;
        acc += W0[o * 34 + 2 + j]  * sinf(arg);
        acc += W0[o * 34 + 18 + j] * cosf(arg);
    }
    cst[k * 512 + o] = acc;
}

__global__ __launch_bounds__(1024)
void flow_kernel(const float* __restrict__ x,
                 const float* __restrict__ w01,
                 const float* __restrict__ cst,
                 const __hip_bfloat16* __restrict__ Wpk1,
                 const __hip_bfloat16* __restrict__ Wpk2,
                 const float* __restrict__ b1,
                 const float* __restrict__ b2,
                 const float* __restrict__ W3,
                 const float* __restrict__ b3v,
                 float* __restrict__ out)
{
    __shared__ __align__(16) __hip_bfloat16 Xbuf[96 * 512];  // 96 KB
    __shared__ float zbuf[32][2];
    __shared__ float ldbuf[32];
    __shared__ __align__(16) float part[16][32][8];          // per-wave W3 partials

    const int tid  = threadIdx.x;
    const int lane = tid & 63;
    const int wid  = tid >> 6;        // 0..15 -> cols [wid*32, wid*32+32)
    const int l31  = lane & 31;
    const int hi   = lane >> 5;       // 0/1
    const int n0w  = wid << 5;
    const int wgs  = blockIdx.x << 5; // 32 samples per WG

    if (tid < 32) {
        zbuf[tid][0] = x[(wgs + tid) * 2 + 0];
        zbuf[tid][1] = x[(wgs + tid) * 2 + 1];
        ldbuf[tid]   = 0.0f;
    }

    // B-frag (X from LDS): rows l31 / 32+l31 / 64+l31; 16B-granule 3-bit swizzle
    const int rowb0 = l31 << 10;
    const int rowb1 = (32 + l31) << 10;
    const int rowb2 = (64 + l31) << 10;
    const int swzB  = (l31 & 7) << 4;
    const int hi16  = hi << 4;
    // A-frag: uint4 index = c*1024 + abase  (wave wid owns n-block wid)
    const int abase = (wid << 6) + lane;
    const uint4* Wp1 = (const uint4*)Wpk1;
    const uint4* Wp2 = (const uint4*)Wpk2;

    // L0 split: s0 = sample (tid>>5, 0..31), t32 = 32-way column split
    const int s0   = tid >> 5;
    const int t32  = tid & 31;
    const int swz0 = (s0 & 7) << 4;

    const char* xb = (const char*)Xbuf;

    __syncthreads();

    #pragma unroll 1
    for (int step = 0; step < 10; ++step) {
        // ---------- layer 0: rank-2 + step-constant, 16 outs/thread ----------
        {
            const float z0 = zbuf[s0][0];
            const float z1 = zbuf[s0][1];
            const float* cs = cst + (step << 9);
            char* base0 = (char*)Xbuf + (s0 << 10);
            #pragma unroll 1
            for (int m = 0; m < 2; ++m) {
                int ob = (t32 << 4) + (m << 3);    // element base, 8 outs
                const float4* wv4 = (const float4*)(w01 + (ob << 1));
                const float4* cv4 = (const float4*)(cs + ob);
                unsigned ph[4], p0[4], p1[4];
                #pragma unroll
                for (int jj = 0; jj < 4; ++jj) {
                    float4 wv = wv4[jj];                    // pairs (x,y),(z,w)
                    float4 cv = cv4[jj >> 1];
                    float c0 = (jj & 1) ? cv.z : cv.x;
                    float c1 = (jj & 1) ? cv.w : cv.y;
                    float a0  = fmaf(z0, wv.x, fmaf(z1, wv.y, c0));
                    float sg0 = 1.0f / (1.0f + __expf(-a0));
                    float h0  = a0 * sg0;
                    float sp0 = fmaf(h0, 1.0f - sg0, sg0);  // silu'(a0)
                    float a1  = fmaf(z0, wv.z, fmaf(z1, wv.w, c1));
                    float sg1 = 1.0f / (1.0f + __expf(-a1));
                    float h1  = a1 * sg1;
                    float sp1 = fmaf(h1, 1.0f - sg1, sg1);
                    ph[jj] = pkbf2(h0, h1);
                    p0[jj] = pkbf2(sp0 * wv.x, sp1 * wv.z);
                    p1[jj] = pkbf2(sp0 * wv.y, sp1 * wv.w);
                }
                int off = (ob << 1) ^ swz0;
                uint4 vph = {ph[0], ph[1], ph[2], ph[3]};
                uint4 vp0 = {p0[0], p0[1], p0[2], p0[3]};
                uint4 vp1 = {p1[0], p1[1], p1[2], p1[3]};
                *(uint4*)(base0 + off)              = vph;
                *(uint4*)(base0 + (32 << 10) + off) = vp0;
                *(uint4*)(base0 + (64 << 10) + off) = vp1;
            }
        }
        __syncthreads();

        // ---------- layers 1,2: D = W @ X^T via 32x32x16 MFMA (intrinsic) ----------
        #pragma unroll 1
        for (int layer = 0; layer < 2; ++layer) {
            const uint4* __restrict__ Wp   = layer ? Wp2 : Wp1;
            const float* __restrict__ bias = layer ? b2  : b1;

            f32x16 acc0 = (f32x16)(0.0f);   // h stream  (AGPR)
            f32x16 acc1 = (f32x16)(0.0f);   // u0
            f32x16 acc2 = (f32x16)(0.0f);   // u1

            // minimal-live K-loop: wrap-around depth-1 A prefetch, B just-in-time.
            uint4 aCur = Wp[abase];
            #pragma unroll 2
            for (int c = 0; c < 32; ++c) {
                uint4 aNxt = Wp[abase + (((c + 1) & 31) << 10)];
                int kx = ((c << 5) | hi16) ^ swzB;
                bf16x8 bf0 = __builtin_bit_cast(bf16x8, *(const uint4*)(xb + rowb0 + kx));
                bf16x8 bf1 = __builtin_bit_cast(bf16x8, *(const uint4*)(xb + rowb1 + kx));
                bf16x8 bf2 = __builtin_bit_cast(bf16x8, *(const uint4*)(xb + rowb2 + kx));
                bf16x8 av  = __builtin_bit_cast(bf16x8, aCur);
                __builtin_amdgcn_s_setprio(1);
                acc0 = __builtin_amdgcn_mfma_f32_32x32x16_bf16(av, bf0, acc0, 0, 0, 0);
                acc1 = __builtin_amdgcn_mfma_f32_32x32x16_bf16(av, bf1, acc1, 0, 0, 0);
                acc2 = __builtin_amdgcn_mfma_f32_32x32x16_bf16(av, bf2, acc2, 0, 0, 0);
                __builtin_amdgcn_s_setprio(0);
                aCur = aNxt;
            }

            if (layer == 0) {
                __syncthreads();   // all waves done reading Xbuf before overwrite
                // epilogue 1: silu + JVP coupling; write next-layer X to LDS.
                // D col = sample = l31; D row n = n0w+(reg&3)+8*(reg>>2)+4*hi
                char* pb = (char*)Xbuf + (l31 << 10);
                #pragma unroll
                for (int q = 0; q < 4; ++q) {
                    int nq = n0w + 8 * q + 4 * hi;          // 4 consecutive n
                    f32x4 bq = *(const f32x4*)(bias + nq);
                    float hv[4], u0v[4], u1v[4];
                    #pragma unroll
                    for (int k = 0; k < 4; ++k) {
                        int reg = 4 * q + k;
                        float aa  = acc0[reg] + bq[k];
                        float sig = 1.0f / (1.0f + __expf(-aa));
                        float h   = aa * sig;
                        float sp  = fmaf(h, 1.0f - sig, sig);
                        hv[k]  = h;
                        u0v[k] = sp * acc1[reg];
                        u1v[k] = sp * acc2[reg];
                    }
                    int off = ((nq << 1) ^ swzB);
                    uint2 vh = {pkbf2(hv[0],  hv[1]),  pkbf2(hv[2],  hv[3])};
                    uint2 v0 = {pkbf2(u0v[0], u0v[1]), pkbf2(u0v[2], u0v[3])};
                    uint2 v1 = {pkbf2(u1v[0], u1v[1]), pkbf2(u1v[2], u1v[3])};
                    *(uint2*)(pb + off)              = vh;
                    *(uint2*)(pb + (32 << 10) + off) = v0;
                    *(uint2*)(pb + (64 << 10) + off) = v1;
                }
                __syncthreads();
            } else {
                // epilogue 2: fold the output projection. Per lane: 6 W3-dots
                // over its 16 cols of sample l31, all register-local.
                float q0 = 0.f, q1 = 0.f, q2 = 0.f, q3 = 0.f, q4 = 0.f, q5 = 0.f;
                #pragma unroll
                for (int q = 0; q < 4; ++q) {
                    int nq = n0w + 8 * q + 4 * hi;
                    f32x4 bq = *(const f32x4*)(bias + nq);
                    f32x4 w0 = *(const f32x4*)(W3 + nq);
                    f32x4 w1 = *(const f32x4*)(W3 + 512 + nq);
                    #pragma unroll
                    for (int k = 0; k < 4; ++k) {
                        int reg = 4 * q + k;
                        float aa  = acc0[reg] + bq[k];
                        float sig = 1.0f / (1.0f + __expf(-aa));
                        float h   = aa * sig;
                        float sp  = fmaf(h, 1.0f - sig, sig);
                        float u0  = sp * acc1[reg];
                        float u1  = sp * acc2[reg];
                        q0 = fmaf(w0[k], h,  q0);
                        q1 = fmaf(w1[k], h,  q1);
                        q2 = fmaf(w0[k], u0, q2);
                        q3 = fmaf(w1[k], u0, q3);
                        q4 = fmaf(w0[k], u1, q4);
                        q5 = fmaf(w1[k], u1, q5);
                    }
                }
                // merge hi halves (same sample l31, disjoint cols)
                q0 += __shfl_xor(q0, 32);
                q1 += __shfl_xor(q1, 32);
                q2 += __shfl_xor(q2, 32);
                q3 += __shfl_xor(q3, 32);
                q4 += __shfl_xor(q4, 32);
                q5 += __shfl_xor(q5, 32);
                if (hi == 0) {
                    float* pp = &part[wid][l31][0];
                    pp[0] = q0; pp[1] = q1; pp[2] = q2;
                    pp[3] = q3; pp[4] = q4; pp[5] = q5;
                }
                __syncthreads();
            }
        }

        // ---------- det + state update: sum 16 wave-partials per sample ----------
        if (tid < 32) {
            float s0v = 0.f, s1v = 0.f, s2v = 0.f, s3v = 0.f, s4v = 0.f, s5v = 0.f;
            #pragma unroll
            for (int w = 0; w < 16; ++w) {
                const float* pp = &part[w][tid][0];
                f32x4 a = *(const f32x4*)(pp);
                f32x4 b = *(const f32x4*)(pp + 4);
                s0v += a[0]; s1v += a[1]; s2v += a[2];
                s3v += a[3]; s4v += b[0]; s5v += b[1];
            }
            float v0 = s0v + b3v[0];
            float v1 = s1v + b3v[1];
            float det = (1.0f + 0.1f * s2v) * (1.0f + 0.1f * s5v)
                      - 0.01f * s4v * s3v;
            ldbuf[tid] += logf(fmaxf(fabsf(det), 1e-8f));
            zbuf[tid][0] += 0.1f * v0;
            zbuf[tid][1] += 0.1f * v1;
        }
        __syncthreads();
    }

    if (tid < 32) {
        float z0 = zbuf[tid][0], z1 = zbuf[tid][1];
        out[wgs + tid] = -0.5f * (z0 * z0 + z1 * z1) - 1.8378770664093453f + ldbuf[tid];
    }
}

extern "C" void kernel_launch(void* const* d_in, const int* in_sizes, int n_in,
                              void* d_out, int out_size, void* d_ws, size_t ws_size,
                              hipStream_t stream) {
    const float* x  = (const float*)d_in[0];
    const float* W0 = (const float*)d_in[1];   // (512, 34)
    const float* b0 = (const float*)d_in[2];
    const float* W1 = (const float*)d_in[3];   // (512, 512)
    const float* b1 = (const float*)d_in[4];
    const float* W2 = (const float*)d_in[5];
    const float* b2 = (const float*)d_in[6];
    const float* W3 = (const float*)d_in[7];   // (2, 512)
    const float* b3 = (const float*)d_in[8];
    float* out = (float*)d_out;

    char* ws = (char*)d_ws;
    __hip_bfloat16* wpk1 = (__hip_bfloat16*)ws;                  // 512 KB
    __hip_bfloat16* wpk2 = (__hip_bfloat16*)(ws + (512u << 10)); // 512 KB
    float*          cstp = (float*)(ws + (1024u << 10));         // 20 KB
    float*          w01p = (float*)(ws + (1044u << 10));         // 4 KB

    pack_w_kernel<<<512, 512, 0, stream>>>(W1, wpk1);
    pack_w_kernel<<<512, 512, 0, stream>>>(W2, wpk2);
    cstep_kernel<<<10, 512, 0, stream>>>(W0, b0, cstp);
    pack_w0_kernel<<<1, 512, 0, stream>>>(W0, w01p);
    flow_kernel<<<131072 / 32, 1024, 0, stream>>>(x, w01p, cstp, wpk1, wpk2,
                                                  b1, b2, W3, b3, out);
}

// Round 18
// 5214.647 us; speedup vs baseline: 1.1443x; 1.0210x over previous
//
#include <hip/hip_runtime.h>
#include <hip/hip_bf16.h>
#include <math.h>

// DiffusionFlow: fused 10-step flow + log-det on MI355X.
// Round 18 = r17 (5.32ms: folded W3 projection, zero-spill, 32 samples/WG,
// 1024 thr / 16 waves, 32x32x16 intrinsic MFMA acc-in-AGPR, minimal-live
// K-loop) + ODD-STRIDE LDS: row stride 1040 B (65 quads) instead of 1024+XOR.
// Quad(row,kb) = row*65 + kb/16 (mod 32): 32 rows -> 32 distinct quads, so
// ds_read_b128 K-reads are conflict-free (64 lanes hit each quad exactly 2x
// = free, m136); epi writes conflict-free; L0 writes 2-way (free). r17's
// 3-bit XOR left a 4-way conflict (5.78e8 cycles ~ 0.9ms of LDS pipe).

typedef float  f32x4  __attribute__((ext_vector_type(4)));
typedef float  f32x16 __attribute__((ext_vector_type(16)));
typedef __bf16 bf16x8 __attribute__((ext_vector_type(8)));

#define ROWB(r) (((r) << 10) + ((r) << 4))   // r * 1040

static __device__ __forceinline__ unsigned pkbf2(float a, float b) {
    unsigned short lo = __builtin_bit_cast(unsigned short, __float2bfloat16(a));
    unsigned short hi = __builtin_bit_cast(unsigned short, __float2bfloat16(b));
    return (unsigned)lo | ((unsigned)hi << 16);
}

// ---- pack W (512x512 row-major fp32) -> bf16 A-frag order for 32x32x16 ----
// out[(((c*16+nb)*64)+l)*8+j] = W[nb*32+(l&31)][c*16+(l>>5)*8+j]  (verified r5-r17)
__global__ void pack_w_kernel(const float* __restrict__ W,
                              __hip_bfloat16* __restrict__ out) {
    int i  = blockIdx.x * 512 + threadIdx.x;
    int c  = i >> 13;
    int nb = (i >> 9) & 15;
    int l  = (i >> 3) & 63;
    int j  = i & 7;
    int n  = nb * 32 + (l & 31);
    int k  = c * 16 + ((l >> 5) << 3) + j;
    out[i] = __float2bfloat16(W[n * 512 + k]);
}

// ---- pack W0 cols 0,1 -> contiguous [512][2] fp32 ----
__global__ void pack_w0_kernel(const float* __restrict__ W0,
                               float* __restrict__ w01) {
    int o = threadIdx.x;
    w01[o * 2 + 0] = W0[o * 34 + 0];
    w01[o * 2 + 1] = W0[o * 34 + 1];
}

// ---- c_step[k][o] = b0[o] + W0[o,2:34] . temb(t_k) ----
__global__ void cstep_kernel(const float* __restrict__ W0,
                             const float* __restrict__ b0,
                             float* __restrict__ cst) {
    int k = blockIdx.x;
    int o = threadIdx.x;
    float t = (float)k * 0.1f;
    float acc = b0[o];
    #pragma unroll
    for (int j = 0; j < 16; ++j) {
        float f   = expf(-9.210340371976184f * (float)j / 16.0f);
        float arg = t * f;
        acc += W0[o * 34 + 2 + j]  * sinf(arg);
        acc += W0[o * 34 + 18 + j] * cosf(arg);
    }
    cst[k * 512 + o] = acc;
}

__global__ __launch_bounds__(1024)
void flow_kernel(const float* __restrict__ x,
                 const float* __restrict__ w01,
                 const float* __restrict__ cst,
                 const __hip_bfloat16* __restrict__ Wpk1,
                 const __hip_bfloat16* __restrict__ Wpk2,
                 const float* __restrict__ b1,
                 const float* __restrict__ b2,
                 const float* __restrict__ W3,
                 const float* __restrict__ b3v,
                 float* __restrict__ out)
{
    __shared__ __align__(16) char Xbuf[96 * 1040];           // 99.8 KB, odd stride
    __shared__ float zbuf[32][2];
    __shared__ float ldbuf[32];
    __shared__ __align__(16) float part[16][32][8];          // per-wave W3 partials

    const int tid  = threadIdx.x;
    const int lane = tid & 63;
    const int wid  = tid >> 6;        // 0..15 -> cols [wid*32, wid*32+32)
    const int l31  = lane & 31;
    const int hi   = lane >> 5;       // 0/1
    const int n0w  = wid << 5;
    const int wgs  = blockIdx.x << 5; // 32 samples per WG

    if (tid < 32) {
        zbuf[tid][0] = x[(wgs + tid) * 2 + 0];
        zbuf[tid][1] = x[(wgs + tid) * 2 + 1];
        ldbuf[tid]   = 0.0f;
    }

    // B-frag (X from LDS): rows l31 / 32+l31 / 64+l31, stride 1040
    const int rowb0 = ROWB(l31);
    const int rowb1 = ROWB(32 + l31);
    const int rowb2 = ROWB(64 + l31);
    const int hi16  = hi << 4;
    // A-frag: uint4 index = c*1024 + abase  (wave wid owns n-block wid)
    const int abase = (wid << 6) + lane;
    const uint4* Wp1 = (const uint4*)Wpk1;
    const uint4* Wp2 = (const uint4*)Wpk2;

    // L0 split: s0 = sample (tid>>5, 0..31), t32 = 32-way column split
    const int s0   = tid >> 5;
    const int t32  = tid & 31;

    const char* xb = (const char*)Xbuf;

    __syncthreads();

    #pragma unroll 1
    for (int step = 0; step < 10; ++step) {
        // ---------- layer 0: rank-2 + step-constant, 16 outs/thread ----------
        {
            const float z0 = zbuf[s0][0];
            const float z1 = zbuf[s0][1];
            const float* cs = cst + (step << 9);
            char* base0 = Xbuf + ROWB(s0);
            #pragma unroll 1
            for (int m = 0; m < 2; ++m) {
                int ob = (t32 << 4) + (m << 3);    // element base, 8 outs
                const float4* wv4 = (const float4*)(w01 + (ob << 1));
                const float4* cv4 = (const float4*)(cs + ob);
                unsigned ph[4], p0[4], p1[4];
                #pragma unroll
                for (int jj = 0; jj < 4; ++jj) {
                    float4 wv = wv4[jj];                    // pairs (x,y),(z,w)
                    float4 cv = cv4[jj >> 1];
                    float c0 = (jj & 1) ? cv.z : cv.x;
                    float c1 = (jj & 1) ? cv.w : cv.y;
                    float a0  = fmaf(z0, wv.x, fmaf(z1, wv.y, c0));
                    float sg0 = 1.0f / (1.0f + __expf(-a0));
                    float h0  = a0 * sg0;
                    float sp0 = fmaf(h0, 1.0f - sg0, sg0);  // silu'(a0)
                    float a1  = fmaf(z0, wv.z, fmaf(z1, wv.w, c1));
                    float sg1 = 1.0f / (1.0f + __expf(-a1));
                    float h1  = a1 * sg1;
                    float sp1 = fmaf(h1, 1.0f - sg1, sg1);
                    ph[jj] = pkbf2(h0, h1);
                    p0[jj] = pkbf2(sp0 * wv.x, sp1 * wv.z);
                    p1[jj] = pkbf2(sp0 * wv.y, sp1 * wv.w);
                }
                int off = ob << 1;
                uint4 vph = {ph[0], ph[1], ph[2], ph[3]};
                uint4 vp0 = {p0[0], p0[1], p0[2], p0[3]};
                uint4 vp1 = {p1[0], p1[1], p1[2], p1[3]};
                *(uint4*)(base0 + off)             = vph;
                *(uint4*)(base0 + ROWB(32) + off)  = vp0;
                *(uint4*)(base0 + ROWB(64) + off)  = vp1;
            }
        }
        __syncthreads();

        // ---------- layers 1,2: D = W @ X^T via 32x32x16 MFMA (intrinsic) ----------
        #pragma unroll 1
        for (int layer = 0; layer < 2; ++layer) {
            const uint4* __restrict__ Wp   = layer ? Wp2 : Wp1;
            const float* __restrict__ bias = layer ? b2  : b1;

            f32x16 acc0 = (f32x16)(0.0f);   // h stream  (AGPR)
            f32x16 acc1 = (f32x16)(0.0f);   // u0
            f32x16 acc2 = (f32x16)(0.0f);   // u1

            // minimal-live K-loop: wrap-around depth-1 A prefetch, B just-in-time.
            uint4 aCur = Wp[abase];
            #pragma unroll 2
            for (int c = 0; c < 32; ++c) {
                uint4 aNxt = Wp[abase + (((c + 1) & 31) << 10)];
                int kx = (c << 5) | hi16;
                bf16x8 bf0 = __builtin_bit_cast(bf16x8, *(const uint4*)(xb + rowb0 + kx));
                bf16x8 bf1 = __builtin_bit_cast(bf16x8, *(const uint4*)(xb + rowb1 + kx));
                bf16x8 bf2 = __builtin_bit_cast(bf16x8, *(const uint4*)(xb + rowb2 + kx));
                bf16x8 av  = __builtin_bit_cast(bf16x8, aCur);
                __builtin_amdgcn_s_setprio(1);
                acc0 = __builtin_amdgcn_mfma_f32_32x32x16_bf16(av, bf0, acc0, 0, 0, 0);
                acc1 = __builtin_amdgcn_mfma_f32_32x32x16_bf16(av, bf1, acc1, 0, 0, 0);
                acc2 = __builtin_amdgcn_mfma_f32_32x32x16_bf16(av, bf2, acc2, 0, 0, 0);
                __builtin_amdgcn_s_setprio(0);
                aCur = aNxt;
            }

            if (layer == 0) {
                __syncthreads();   // all waves done reading Xbuf before overwrite
                // epilogue 1: silu + JVP coupling; write next-layer X to LDS.
                // D col = sample = l31; D row n = n0w+(reg&3)+8*(reg>>2)+4*hi
                char* pb = Xbuf + ROWB(l31);
                #pragma unroll
                for (int q = 0; q < 4; ++q) {
                    int nq = n0w + 8 * q + 4 * hi;          // 4 consecutive n
                    f32x4 bq = *(const f32x4*)(bias + nq);
                    float hv[4], u0v[4], u1v[4];
                    #pragma unroll
                    for (int k = 0; k < 4; ++k) {
                        int reg = 4 * q + k;
                        float aa  = acc0[reg] + bq[k];
                        float sig = 1.0f / (1.0f + __expf(-aa));
                        float h   = aa * sig;
                        float sp  = fmaf(h, 1.0f - sig, sig);
                        hv[k]  = h;
                        u0v[k] = sp * acc1[reg];
                        u1v[k] = sp * acc2[reg];
                    }
                    int off = nq << 1;
                    uint2 vh = {pkbf2(hv[0],  hv[1]),  pkbf2(hv[2],  hv[3])};
                    uint2 v0 = {pkbf2(u0v[0], u0v[1]), pkbf2(u0v[2], u0v[3])};
                    uint2 v1 = {pkbf2(u1v[0], u1v[1]), pkbf2(u1v[2], u1v[3])};
                    *(uint2*)(pb + off)            = vh;
                    *(uint2*)(pb + ROWB(32) + off) = v0;
                    *(uint2*)(pb + ROWB(64) + off) = v1;
                }
                __syncthreads();
            } else {
                // epilogue 2: folded output projection (register-local W3 dots)
                float q0 = 0.f, q1 = 0.f, q2 = 0.f, q3 = 0.f, q4 = 0.f, q5 = 0.f;
                #pragma unroll
                for (int q = 0; q < 4; ++q) {
                    int nq = n0w + 8 * q + 4 * hi;
                    f32x4 bq = *(const f32x4*)(bias + nq);
                    f32x4 w0 = *(const f32x4*)(W3 + nq);
                    f32x4 w1 = *(const f32x4*)(W3 + 512 + nq);
                    #pragma unroll
                    for (int k = 0; k < 4; ++k) {
                        int reg = 4 * q + k;
                        float aa  = acc0[reg] + bq[k];
                        float sig = 1.0f / (1.0f + __expf(-aa));
                        float h   = aa * sig;
                        float sp  = fmaf(h, 1.0f - sig, sig);
                        float u0  = sp * acc1[reg];
                        float u1  = sp * acc2[reg];
                        q0 = fmaf(w0[k], h,  q0);
                        q1 = fmaf(w1[k], h,  q1);
                        q2 = fmaf(w0[k], u0, q2);
                        q3 = fmaf(w1[k], u0, q3);
                        q4 = fmaf(w0[k], u1, q4);
                        q5 = fmaf(w1[k], u1, q5);
                    }
                }
                q0 += __shfl_xor(q0, 32);
                q1 += __shfl_xor(q1, 32);
                q2 += __shfl_xor(q2, 32);
                q3 += __shfl_xor(q3, 32);
                q4 += __shfl_xor(q4, 32);
                q5 += __shfl_xor(q5, 32);
                if (hi == 0) {
                    float* pp = &part[wid][l31][0];
                    pp[0] = q0; pp[1] = q1; pp[2] = q2;
                    pp[3] = q3; pp[4] = q4; pp[5] = q5;
                }
                __syncthreads();
            }
        }

        // ---------- det + state update: sum 16 wave-partials per sample ----------
        if (tid < 32) {
            float s0v = 0.f, s1v = 0.f, s2v = 0.f, s3v = 0.f, s4v = 0.f, s5v = 0.f;
            #pragma unroll
            for (int w = 0; w < 16; ++w) {
                const float* pp = &part[w][tid][0];
                f32x4 a = *(const f32x4*)(pp);
                f32x4 b = *(const f32x4*)(pp + 4);
                s0v += a[0]; s1v += a[1]; s2v += a[2];
                s3v += a[3]; s4v += b[0]; s5v += b[1];
            }
            float v0 = s0v + b3v[0];
            float v1 = s1v + b3v[1];
            float det = (1.0f + 0.1f * s2v) * (1.0f + 0.1f * s5v)
                      - 0.01f * s4v * s3v;
            ldbuf[tid] += logf(fmaxf(fabsf(det), 1e-8f));
            zbuf[tid][0] += 0.1f * v0;
            zbuf[tid][1] += 0.1f * v1;
        }
        __syncthreads();
    }

    if (tid < 32) {
        float z0 = zbuf[tid][0], z1 = zbuf[tid][1];
        out[wgs + tid] = -0.5f * (z0 * z0 + z1 * z1) - 1.8378770664093453f + ldbuf[tid];
    }
}

extern "C" void kernel_launch(void* const* d_in, const int* in_sizes, int n_in,
                              void* d_out, int out_size, void* d_ws, size_t ws_size,
                              hipStream_t stream) {
    const float* x  = (const float*)d_in[0];
    const float* W0 = (const float*)d_in[1];   // (512, 34)
    const float* b0 = (const float*)d_in[2];
    const float* W1 = (const float*)d_in[3];   // (512, 512)
    const float* b1 = (const float*)d_in[4];
    const float* W2 = (const float*)d_in[5];
    const float* b2 = (const float*)d_in[6];
    const float* W3 = (const float*)d_in[7];   // (2, 512)
    const float* b3 = (const float*)d_in[8];
    float* out = (float*)d_out;

    char* ws = (char*)d_ws;
    __hip_bfloat16* wpk1 = (__hip_bfloat16*)ws;                  // 512 KB
    __hip_bfloat16* wpk2 = (__hip_bfloat16*)(ws + (512u << 10)); // 512 KB
    float*          cstp = (float*)(ws + (1024u << 10));         // 20 KB
    float*          w01p = (float*)(ws + (1044u << 10));         // 4 KB

    pack_w_kernel<<<512, 512, 0, stream>>>(W1, wpk1);
    pack_w_kernel<<<512, 512, 0, stream>>>(W2, wpk2);
    cstep_kernel<<<10, 512, 0, stream>>>(W0, b0, cstp);
    pack_w0_kernel<<<1, 512, 0, stream>>>(W0, w01p);
    flow_kernel<<<131072 / 32, 1024, 0, stream>>>(x, w01p, cstp, wpk1, wpk2,
                                                  b1, b2, W3, b3, out);
}

// Round 19
// 4950.648 us; speedup vs baseline: 1.2054x; 1.0533x over previous
//
#include <hip/hip_runtime.h>
#include <hip/hip_bf16.h>
#include <math.h>

// DiffusionFlow: fused 10-step flow + log-det on MI355X.
// Round 19: cut the dominant pipe (K-loop LDS B-reads, 15.4us/step vs MFMA
// 10.2us). 512 thr / 8 waves; wave owns 64 cols (2 n-tiles) x all 96 rows:
// per c-iter 2 A-frags + 3 B-frags -> 6 MFMAs, so B-bytes/MFMA halve and
// per-CU LDS traffic drops 3MB -> 1.5MB/step (7.7us < MFMA) = MFMA-bound.
// acc = 6 f32x16 = 96 AGPR + ~80 arch (no attrs; r7 precedent: allocator
// gives what's demanded at 512thr without spilling). Everything else = r18:
// 1040B odd-stride LDS (conflict-free), folded W3 projection, minimal-live
// wrap-around prefetch K-loop, register-lean L0.

typedef float  f32x4  __attribute__((ext_vector_type(4)));
typedef float  f32x16 __attribute__((ext_vector_type(16)));
typedef __bf16 bf16x8 __attribute__((ext_vector_type(8)));

#define ROWB(r) (((r) << 10) + ((r) << 4))   // r * 1040

static __device__ __forceinline__ unsigned pkbf2(float a, float b) {
    unsigned short lo = __builtin_bit_cast(unsigned short, __float2bfloat16(a));
    unsigned short hi = __builtin_bit_cast(unsigned short, __float2bfloat16(b));
    return (unsigned)lo | ((unsigned)hi << 16);
}

// ---- pack W (512x512 row-major fp32) -> bf16 A-frag order for 32x32x16 ----
// out[(((c*16+nb)*64)+l)*8+j] = W[nb*32+(l&31)][c*16+(l>>5)*8+j]  (verified r5-r18)
__global__ void pack_w_kernel(const float* __restrict__ W,
                              __hip_bfloat16* __restrict__ out) {
    int i  = blockIdx.x * 512 + threadIdx.x;
    int c  = i >> 13;
    int nb = (i >> 9) & 15;
    int l  = (i >> 3) & 63;
    int j  = i & 7;
    int n  = nb * 32 + (l & 31);
    int k  = c * 16 + ((l >> 5) << 3) + j;
    out[i] = __float2bfloat16(W[n * 512 + k]);
}

// ---- pack W0 cols 0,1 -> contiguous [512][2] fp32 ----
__global__ void pack_w0_kernel(const float* __restrict__ W0,
                               float* __restrict__ w01) {
    int o = threadIdx.x;
    w01[o * 2 + 0] = W0[o * 34 + 0];
    w01[o * 2 + 1] = W0[o * 34 + 1];
}

// ---- c_step[k][o] = b0[o] + W0[o,2:34] . temb(t_k) ----
__global__ void cstep_kernel(const float* __restrict__ W0,
                             const float* __restrict__ b0,
                             float* __restrict__ cst) {
    int k = blockIdx.x;
    int o = threadIdx.x;
    float t = (float)k * 0.1f;
    float acc = b0[o];
    #pragma unroll
    for (int j = 0; j < 16; ++j) {
        float f   = expf(-9.210340371976184f * (float)j / 16.0f);
        float arg = t * f;
        acc += W0[o * 34 + 2 + j]  * sinf(arg);
        acc += W0[o * 34 + 18 + j] * cosf(arg);
    }
    cst[k * 512 + o] = acc;
}

__global__ __launch_bounds__(512)
void flow_kernel(const float* __restrict__ x,
                 const float* __restrict__ w01,
                 const float* __restrict__ cst,
                 const __hip_bfloat16* __restrict__ Wpk1,
                 const __hip_bfloat16* __restrict__ Wpk2,
                 const float* __restrict__ b1,
                 const float* __restrict__ b2,
                 const float* __restrict__ W3,
                 const float* __restrict__ b3v,
                 float* __restrict__ out)
{
    __shared__ __align__(16) char Xbuf[96 * 1040];           // 99.8 KB, odd stride
    __shared__ float zbuf[32][2];
    __shared__ float ldbuf[32];
    __shared__ __align__(16) float part[8][32][8];           // per-wave W3 partials

    const int tid  = threadIdx.x;
    const int lane = tid & 63;
    const int wid  = tid >> 6;        // 0..7 -> cols [wid*64, wid*64+64)
    const int l31  = lane & 31;
    const int hi   = lane >> 5;       // 0/1
    const int n0w  = wid << 6;
    const int wgs  = blockIdx.x << 5; // 32 samples per WG

    if (tid < 32) {
        zbuf[tid][0] = x[(wgs + tid) * 2 + 0];
        zbuf[tid][1] = x[(wgs + tid) * 2 + 1];
        ldbuf[tid]   = 0.0f;
    }

    // B-frag (X from LDS): rows l31 / 32+l31 / 64+l31, stride 1040
    const int rowb0 = ROWB(l31);
    const int rowb1 = ROWB(32 + l31);
    const int rowb2 = ROWB(64 + l31);
    const int hi16  = hi << 4;
    // A-frags: uint4 index = c*1024 + abase (+64 for 2nd n-tile)
    const int abase = (wid << 7) + lane;
    const uint4* Wp1 = (const uint4*)Wpk1;
    const uint4* Wp2 = (const uint4*)Wpk2;

    // L0 split: s0 = sample (tid>>4, 0..31), t16 = 16-way column split
    const int s0  = tid >> 4;
    const int t16 = tid & 15;

    const char* xb = (const char*)Xbuf;

    __syncthreads();

    #pragma unroll 1
    for (int step = 0; step < 10; ++step) {
        // ---------- layer 0: rank-2 + step-constant, 32 outs/thread ----------
        {
            const float z0 = zbuf[s0][0];
            const float z1 = zbuf[s0][1];
            const float* cs = cst + (step << 9);
            char* base0 = Xbuf + ROWB(s0);
            #pragma unroll 1
            for (int m = 0; m < 4; ++m) {
                int ob = (t16 << 5) + (m << 3);    // element base, 8 outs
                const float4* wv4 = (const float4*)(w01 + (ob << 1));
                const float4* cv4 = (const float4*)(cs + ob);
                unsigned ph[4], p0[4], p1[4];
                #pragma unroll
                for (int jj = 0; jj < 4; ++jj) {
                    float4 wv = wv4[jj];                    // pairs (x,y),(z,w)
                    float4 cv = cv4[jj >> 1];
                    float c0 = (jj & 1) ? cv.z : cv.x;
                    float c1 = (jj & 1) ? cv.w : cv.y;
                    float a0  = fmaf(z0, wv.x, fmaf(z1, wv.y, c0));
                    float sg0 = 1.0f / (1.0f + __expf(-a0));
                    float h0  = a0 * sg0;
                    float sp0 = fmaf(h0, 1.0f - sg0, sg0);  // silu'(a0)
                    float a1  = fmaf(z0, wv.z, fmaf(z1, wv.w, c1));
                    float sg1 = 1.0f / (1.0f + __expf(-a1));
                    float h1  = a1 * sg1;
                    float sp1 = fmaf(h1, 1.0f - sg1, sg1);
                    ph[jj] = pkbf2(h0, h1);
                    p0[jj] = pkbf2(sp0 * wv.x, sp1 * wv.z);
                    p1[jj] = pkbf2(sp0 * wv.y, sp1 * wv.w);
                }
                int off = ob << 1;
                uint4 vph = {ph[0], ph[1], ph[2], ph[3]};
                uint4 vp0 = {p0[0], p0[1], p0[2], p0[3]};
                uint4 vp1 = {p1[0], p1[1], p1[2], p1[3]};
                *(uint4*)(base0 + off)             = vph;
                *(uint4*)(base0 + ROWB(32) + off)  = vp0;
                *(uint4*)(base0 + ROWB(64) + off)  = vp1;
            }
        }
        __syncthreads();

        // ---------- layers 1,2: D = W @ X^T via 32x32x16 MFMA (intrinsic) ----------
        #pragma unroll 1
        for (int layer = 0; layer < 2; ++layer) {
            const uint4* __restrict__ Wp   = layer ? Wp2 : Wp1;
            const float* __restrict__ bias = layer ? b2  : b1;

            // [n-tile][stream], AGPR
            f32x16 acc00 = (f32x16)(0.0f), acc01 = (f32x16)(0.0f), acc02 = (f32x16)(0.0f);
            f32x16 acc10 = (f32x16)(0.0f), acc11 = (f32x16)(0.0f), acc12 = (f32x16)(0.0f);

            // minimal-live K-loop: wrap-around depth-1 A prefetch, B just-in-time.
            uint4 aCur0 = Wp[abase];
            uint4 aCur1 = Wp[abase + 64];
            #pragma unroll 2
            for (int c = 0; c < 32; ++c) {
                int nidx = abase + (((c + 1) & 31) << 10);
                uint4 aNxt0 = Wp[nidx];
                uint4 aNxt1 = Wp[nidx + 64];
                int kx = (c << 5) | hi16;
                bf16x8 bf0 = __builtin_bit_cast(bf16x8, *(const uint4*)(xb + rowb0 + kx));
                bf16x8 bf1 = __builtin_bit_cast(bf16x8, *(const uint4*)(xb + rowb1 + kx));
                bf16x8 bf2 = __builtin_bit_cast(bf16x8, *(const uint4*)(xb + rowb2 + kx));
                bf16x8 av0 = __builtin_bit_cast(bf16x8, aCur0);
                bf16x8 av1 = __builtin_bit_cast(bf16x8, aCur1);
                __builtin_amdgcn_s_setprio(1);
                acc00 = __builtin_amdgcn_mfma_f32_32x32x16_bf16(av0, bf0, acc00, 0, 0, 0);
                acc10 = __builtin_amdgcn_mfma_f32_32x32x16_bf16(av1, bf0, acc10, 0, 0, 0);
                acc01 = __builtin_amdgcn_mfma_f32_32x32x16_bf16(av0, bf1, acc01, 0, 0, 0);
                acc11 = __builtin_amdgcn_mfma_f32_32x32x16_bf16(av1, bf1, acc11, 0, 0, 0);
                acc02 = __builtin_amdgcn_mfma_f32_32x32x16_bf16(av0, bf2, acc02, 0, 0, 0);
                acc12 = __builtin_amdgcn_mfma_f32_32x32x16_bf16(av1, bf2, acc12, 0, 0, 0);
                __builtin_amdgcn_s_setprio(0);
                aCur0 = aNxt0;
                aCur1 = aNxt1;
            }

            if (layer == 0) {
                __syncthreads();   // all waves done reading Xbuf before overwrite
                // epilogue 1: silu + JVP coupling; write next-layer X to LDS.
                // D col = sample = l31; D row n = n0w+nt*32+(reg&3)+8*(reg>>2)+4*hi
                char* pb = Xbuf + ROWB(l31);
                #pragma unroll
                for (int nt = 0; nt < 2; ++nt) {
                    const f32x16& a0r = nt ? acc10 : acc00;
                    const f32x16& a1r = nt ? acc11 : acc01;
                    const f32x16& a2r = nt ? acc12 : acc02;
                    #pragma unroll
                    for (int q = 0; q < 4; ++q) {
                        int nq = n0w + nt * 32 + 8 * q + 4 * hi;  // 4 consecutive n
                        f32x4 bq = *(const f32x4*)(bias + nq);
                        float hv[4], u0v[4], u1v[4];
                        #pragma unroll
                        for (int k = 0; k < 4; ++k) {
                            int reg = 4 * q + k;
                            float aa  = a0r[reg] + bq[k];
                            float sig = 1.0f / (1.0f + __expf(-aa));
                            float h   = aa * sig;
                            float sp  = fmaf(h, 1.0f - sig, sig);
                            hv[k]  = h;
                            u0v[k] = sp * a1r[reg];
                            u1v[k] = sp * a2r[reg];
                        }
                        int off = nq << 1;
                        uint2 vh = {pkbf2(hv[0],  hv[1]),  pkbf2(hv[2],  hv[3])};
                        uint2 v0 = {pkbf2(u0v[0], u0v[1]), pkbf2(u0v[2], u0v[3])};
                        uint2 v1 = {pkbf2(u1v[0], u1v[1]), pkbf2(u1v[2], u1v[3])};
                        *(uint2*)(pb + off)            = vh;
                        *(uint2*)(pb + ROWB(32) + off) = v0;
                        *(uint2*)(pb + ROWB(64) + off) = v1;
                    }
                }
                __syncthreads();
            } else {
                // epilogue 2: folded output projection (register-local W3 dots)
                float q0 = 0.f, q1 = 0.f, q2 = 0.f, q3 = 0.f, q4 = 0.f, q5 = 0.f;
                #pragma unroll
                for (int nt = 0; nt < 2; ++nt) {
                    const f32x16& a0r = nt ? acc10 : acc00;
                    const f32x16& a1r = nt ? acc11 : acc01;
                    const f32x16& a2r = nt ? acc12 : acc02;
                    #pragma unroll
                    for (int q = 0; q < 4; ++q) {
                        int nq = n0w + nt * 32 + 8 * q + 4 * hi;
                        f32x4 bq = *(const f32x4*)(bias + nq);
                        f32x4 w0 = *(const f32x4*)(W3 + nq);
                        f32x4 w1 = *(const f32x4*)(W3 + 512 + nq);
                        #pragma unroll
                        for (int k = 0; k < 4; ++k) {
                            int reg = 4 * q + k;
                            float aa  = a0r[reg] + bq[k];
                            float sig = 1.0f / (1.0f + __expf(-aa));
                            float h   = aa * sig;
                            float sp  = fmaf(h, 1.0f - sig, sig);
                            float u0  = sp * a1r[reg];
                            float u1  = sp * a2r[reg];
                            q0 = fmaf(w0[k], h,  q0);
                            q1 = fmaf(w1[k], h,  q1);
                            q2 = fmaf(w0[k], u0, q2);
                            q3 = fmaf(w1[k], u0, q3);
                            q4 = fmaf(w0[k], u1, q4);
                            q5 = fmaf(w1[k], u1, q5);
                        }
                    }
                }
                q0 += __shfl_xor(q0, 32);
                q1 += __shfl_xor(q1, 32);
                q2 += __shfl_xor(q2, 32);
                q3 += __shfl_xor(q3, 32);
                q4 += __shfl_xor(q4, 32);
                q5 += __shfl_xor(q5, 32);
                if (hi == 0) {
                    float* pp = &part[wid][l31][0];
                    pp[0] = q0; pp[1] = q1; pp[2] = q2;
                    pp[3] = q3; pp[4] = q4; pp[5] = q5;
                }
                __syncthreads();
            }
        }

        // ---------- det + state update: sum 8 wave-partials per sample ----------
        if (tid < 32) {
            float s0v = 0.f, s1v = 0.f, s2v = 0.f, s3v = 0.f, s4v = 0.f, s5v = 0.f;
            #pragma unroll
            for (int w = 0; w < 8; ++w) {
                const float* pp = &part[w][tid][0];
                f32x4 a = *(const f32x4*)(pp);
                f32x4 b = *(const f32x4*)(pp + 4);
                s0v += a[0]; s1v += a[1]; s2v += a[2];
                s3v += a[3]; s4v += b[0]; s5v += b[1];
            }
            float v0 = s0v + b3v[0];
            float v1 = s1v + b3v[1];
            float det = (1.0f + 0.1f * s2v) * (1.0f + 0.1f * s5v)
                      - 0.01f * s4v * s3v;
            ldbuf[tid] += logf(fmaxf(fabsf(det), 1e-8f));
            zbuf[tid][0] += 0.1f * v0;
            zbuf[tid][1] += 0.1f * v1;
        }
        __syncthreads();
    }

    if (tid < 32) {
        float z0 = zbuf[tid][0], z1 = zbuf[tid][1];
        out[wgs + tid] = -0.5f * (z0 * z0 + z1 * z1) - 1.8378770664093453f + ldbuf[tid];
    }
}

extern "C" void kernel_launch(void* const* d_in, const int* in_sizes, int n_in,
                              void* d_out, int out_size, void* d_ws, size_t ws_size,
                              hipStream_t stream) {
    const float* x  = (const float*)d_in[0];
    const float* W0 = (const float*)d_in[1];   // (512, 34)
    const float* b0 = (const float*)d_in[2];
    const float* W1 = (const float*)d_in[3];   // (512, 512)
    const float* b1 = (const float*)d_in[4];
    const float* W2 = (const float*)d_in[5];
    const float* b2 = (const float*)d_in[6];
    const float* W3 = (const float*)d_in[7];   // (2, 512)
    const float* b3 = (const float*)d_in[8];
    float* out = (float*)d_out;

    char* ws = (char*)d_ws;
    __hip_bfloat16* wpk1 = (__hip_bfloat16*)ws;                  // 512 KB
    __hip_bfloat16* wpk2 = (__hip_bfloat16*)(ws + (512u << 10)); // 512 KB
    float*          cstp = (float*)(ws + (1024u << 10));         // 20 KB
    float*          w01p = (float*)(ws + (1044u << 10));         // 4 KB

    pack_w_kernel<<<512, 512, 0, stream>>>(W1, wpk1);
    pack_w_kernel<<<512, 512, 0, stream>>>(W2, wpk2);
    cstep_kernel<<<10, 512, 0, stream>>>(W0, b0, cstp);
    pack_w0_kernel<<<1, 512, 0, stream>>>(W0, w01p);
    flow_kernel<<<131072 / 32, 512, 0, stream>>>(x, w01p, cstp, wpk1, wpk2,
                                                 b1, b2, W3, b3, out);
}